// Round 1
// baseline (212.917 us; speedup 1.0000x reference)
//
#include <hip/hip_runtime.h>
#include <hip/hip_bf16.h>
#include <math.h>

#define NB 64      // batch
#define NN 576     // patches
#define ND 512     // dim
#define NM 16      // nouns
#define QPB 9      // fine blocks per batch element
#define NPB 64     // patches per fine block
#define CH 32      // floats per chunk (per patch)
#define NCH 16     // chunks (16*32 = 512)
#define LSTR 33    // padded LDS row stride (floats) -> conflict-free b32
#define KPOS 5
#define TINV 14.2857142857142857f   // 1/0.07

#define WS_REC_OFF 4096             // after 64*64 scores
#define RECSZ 144                   // floats per fine-block record

#define FINF __builtin_inff()

// insert v into desc-sorted 5-list (constant indices only -> stays in VGPRs)
__device__ __forceinline__ void ins5(float (&a)[5], float v) {
  if (v > a[4]) {
    a[4] = v;
    if (a[4] > a[3]) { float x = a[4]; a[4] = a[3]; a[3] = x; }
    if (a[3] > a[2]) { float x = a[3]; a[3] = a[2]; a[2] = x; }
    if (a[2] > a[1]) { float x = a[2]; a[2] = a[1]; a[1] = x; }
    if (a[1] > a[0]) { float x = a[1]; a[1] = a[0]; a[0] = x; }
  }
}

// top-5 of union of two desc-sorted 5-lists, branch-free fixed-index rank merge:
// m[k] = max_{i+j=k+1} min(Ae[i], Be[j]), Ae[0]=Be[0]=+inf
__device__ __forceinline__ void merge5(float (&a)[5], const float (&b)[5]) {
  float r[5];
#pragma unroll
  for (int k = 0; k < 5; ++k) {
    float best = -FINF;
#pragma unroll
    for (int i = 0; i <= k + 1; ++i) {
      const int j = k + 1 - i;
      const float av = (i == 0) ? FINF : a[i - 1];
      const float bv = (j == 0) ? FINF : b[j - 1];
      best = fmaxf(best, fminf(av, bv));
    }
    r[k] = best;
  }
#pragma unroll
  for (int k = 0; k < 5; ++k) a[k] = r[k];
}

__global__ __launch_bounds__(64) void k_main(
    const float* __restrict__ patch, const float* __restrict__ noun,
    const float* __restrict__ gimg, const float* __restrict__ gtxt,
    float* __restrict__ ws) {
  const int blk = blockIdx.x;
  const int t = threadIdx.x;

  if (blk >= NB * QPB) {
    // ---- score block: scores[i][j] = <img_i, txt_j> ----
    const int i = blk - NB * QPB;
    const float4* ip = (const float4*)(gimg + (size_t)i * ND);
    const float4* tp = (const float4*)(gtxt + (size_t)t * ND);
    float acc = 0.f;
#pragma unroll 8
    for (int q = 0; q < ND / 4; ++q) {
      const float4 a = ip[q];
      const float4 b = tp[q];
      acc += a.x * b.x + a.y * b.y + a.z * b.z + a.w * b.w;
    }
    ws[i * 64 + t] = acc;
    return;
  }

  // ---- fine block: b, 64-patch slice ----
  const int b = blk / QPB;
  const int quad = blk - b * QPB;
  const int n0 = quad * NPB;

  __shared__ float lds[NPB * LSTR];        // 8448 B staged patch chunk
  __shared__ float sim[NM * (NPB + 1)];    // 4160 B scaled sim tile

  const float* pbase = patch + ((size_t)b * NN + (size_t)n0) * ND;
  const float* nbase = noun + (size_t)b * NM * ND;

  float acc[NM];
#pragma unroll
  for (int m = 0; m < NM; ++m) acc[m] = 0.f;

  const int sp = t >> 3;   // staging patch (within group of 8)
  const int sf = t & 7;    // staging float4 index

  float4 stg[8];
#pragma unroll
  for (int r = 0; r < 8; ++r)
    stg[r] = *(const float4*)(pbase + (size_t)(8 * r + sp) * ND + sf * 4);

  for (int c = 0; c < NCH; ++c) {
    __syncthreads();
#pragma unroll
    for (int r = 0; r < 8; ++r) {
      float* dst = &lds[(8 * r + sp) * LSTR + sf * 4];
      dst[0] = stg[r].x; dst[1] = stg[r].y; dst[2] = stg[r].z; dst[3] = stg[r].w;
    }
    __syncthreads();
    if (c + 1 < NCH) {
      const float* pb2 = pbase + (size_t)(c + 1) * CH;
#pragma unroll
      for (int r = 0; r < 8; ++r)
        stg[r] = *(const float4*)(pb2 + (size_t)(8 * r + sp) * ND + sf * 4);
    }
    // lane owns patch column t; pull chunk to registers
    float pf[CH];
#pragma unroll
    for (int d = 0; d < CH; ++d) pf[d] = lds[t * LSTR + d];
    const float* nc = nbase + c * CH;   // block-uniform address -> s_load expected
#pragma unroll 4
    for (int m = 0; m < NM; ++m) {
      const float* np_ = nc + m * ND;
      float s0 = 0.f, s1 = 0.f;
#pragma unroll
      for (int d = 0; d < CH; d += 2) {
        s0 += pf[d] * np_[d];
        s1 += pf[d + 1] * np_[d + 1];
      }
      acc[m] += s0 + s1;
    }
  }

  // scaled domain: scaled = sim/T ; pooled/T = mean_m scaled
  float x = 0.f;
#pragma unroll
  for (int m = 0; m < NM; ++m) { acc[m] *= TINV; x += acc[m]; }
  x *= (1.f / 16.f);

#pragma unroll
  for (int m = 0; m < NM; ++m) sim[m * (NPB + 1) + t] = acc[m];

  float* rec = ws + WS_REC_OFF + (size_t)blk * RECSZ;

  // ---- phase 3: mask partials (softplus sum + top5 of pooled), shuffles only ----
  float sxp = (x > 0.f) ? (x + log1pf(expf(-x))) : log1pf(expf(x));
  float t5[5] = {x, -FINF, -FINF, -FINF, -FINF};
#pragma unroll
  for (int msk = 1; msk < 64; msk <<= 1) {
    sxp += __shfl_xor(sxp, msk, 64);
    float o[5];
#pragma unroll
    for (int k = 0; k < 5; ++k) o[k] = __shfl_xor(t5[k], msk, 64);
    merge5(t5, o);
  }
  if (t == 0) {
    rec[128] = sxp;
#pragma unroll
    for (int k = 0; k < 5; ++k) rec[129 + k] = t5[k];
  }

  __syncthreads();

  // ---- phase 2: per-noun row stats over 64 cols (16 rows x 4 segments) ----
  const int r = t & 15;
  const int h = t >> 4;
  const float* row = &sim[r * (NPB + 1) + h * 16];
  float mx = -FINF;
#pragma unroll
  for (int k = 0; k < 16; ++k) mx = fmaxf(mx, row[k]);
  mx = fmaxf(mx, __shfl_xor(mx, 16, 64));
  mx = fmaxf(mx, __shfl_xor(mx, 32, 64));
  float se = 0.f;
  float r5[5] = {-FINF, -FINF, -FINF, -FINF, -FINF};
#pragma unroll
  for (int k = 0; k < 16; ++k) {
    const float v = row[k];
    se += expf(v - mx);
    ins5(r5, v);
  }
  se += __shfl_xor(se, 16, 64);
  se += __shfl_xor(se, 32, 64);
  {
    float o[5];
#pragma unroll
    for (int k = 0; k < 5; ++k) o[k] = __shfl_xor(r5[k], 16, 64);
    merge5(r5, o);
#pragma unroll
    for (int k = 0; k < 5; ++k) o[k] = __shfl_xor(r5[k], 32, 64);
    merge5(r5, o);
  }
  if (h == 0) {
    float* rr = rec + r * 8;
    rr[0] = mx;
    rr[1] = se;
#pragma unroll
    for (int k = 0; k < 5; ++k) rr[2 + k] = r5[k];
  }
}

__global__ __launch_bounds__(64) void k_final(
    const float* __restrict__ ws, const float* __restrict__ lscale,
    const int* __restrict__ idx, float* __restrict__ out) {
  const int blk = blockIdx.x;
  const int t = threadIdx.x;

  if (blk < NB) {
    // ---- merge the 9 quad partials for batch element blk ----
    const float* base = ws + WS_REC_OFF + (size_t)blk * QPB * RECSZ;
    float contrib = 0.f;
    if (t < NM) {
      float mx = -FINF;
#pragma unroll
      for (int q = 0; q < QPB; ++q) mx = fmaxf(mx, base[q * RECSZ + t * 8]);
      float S = 0.f;
      float t5[5] = {-FINF, -FINF, -FINF, -FINF, -FINF};
#pragma unroll
      for (int q = 0; q < QPB; ++q) {
        const float* rr = base + q * RECSZ + t * 8;
        S += rr[1] * expf(rr[0] - mx);
#pragma unroll
        for (int k = 0; k < 5; ++k) ins5(t5, rr[2 + k]);
      }
      const float lse = mx + logf(S);
      const float st = t5[0] + t5[1] + t5[2] + t5[3] + t5[4];
      contrib = (KPOS * lse - st) * (0.6f / (float)(NB * NM));
    } else if (t == 16) {
      float sp = 0.f;
      float t5[5] = {-FINF, -FINF, -FINF, -FINF, -FINF};
#pragma unroll
      for (int q = 0; q < QPB; ++q) {
        const float* rr = base + q * RECSZ + 128;
        sp += rr[0];
#pragma unroll
        for (int k = 0; k < 5; ++k) ins5(t5, rr[1 + k]);
      }
      const float st = t5[0] + t5[1] + t5[2] + t5[3] + t5[4];
      contrib = (sp - st) * (0.4f / (float)(NB * NN));
    }
#pragma unroll
    for (int msk = 1; msk < 64; msk <<= 1) contrib += __shfl_xor(contrib, msk, 64);
    if (t == 0) atomicAdd(out + 2, contrib);
    return;
  }

  // ---- loss_c (CLIP bi-directional CE) + loss_t (triplet), from scores ----
  __shared__ float s[64 * 65];
  __shared__ float dg[64];
  __shared__ int idl[64];
  for (int i = 0; i < 64; ++i) s[i * 65 + t] = ws[i * 64 + t];
  idl[t] = idx[t];
  __syncthreads();
  dg[t] = s[t * 66];
  __syncthreads();
  const float sc = lscale[0];

  float mR = -FINF, mC = -FINF;
  for (int j = 0; j < 64; ++j) {
    mR = fmaxf(mR, sc * s[t * 65 + j]);
    mC = fmaxf(mC, sc * s[j * 65 + t]);
  }
  float seR = 0.f, seC = 0.f;
  for (int j = 0; j < 64; ++j) {
    seR += expf(sc * s[t * 65 + j] - mR);
    seC += expf(sc * s[j * 65 + t] - mC);
  }
  const float lseR = mR + logf(seR);
  const float lseC = mC + logf(seC);

  const int myid = idl[t];
  const float di = dg[t];
  float ps = 0.f, trow = 0.f, tcol = 0.f, cs = 0.f, ci = 0.f;
  for (int j = 0; j < 64; ++j) {
    const float sv = s[t * 65 + j];
    const float svT = s[j * 65 + t];
    if (idl[j] == myid) {
      ps += 1.f;
      trow += sc * sv - lseR;
      tcol += sc * svT - lseC;
    }
    if (j != t) {
      cs += fmaxf(0.f, 0.1f + sv - di);
      ci += fmaxf(0.f, 0.1f + sv - dg[j]);
    }
  }
  float vc = -(trow + tcol) / ps;  // li2t_i + lt2i_i
  float vt = cs + ci;
#pragma unroll
  for (int msk = 1; msk < 64; msk <<= 1) {
    vc += __shfl_xor(vc, msk, 64);
    vt += __shfl_xor(vt, msk, 64);
  }
  if (t == 0) {
    out[0] = vc * (0.5f / 64.f);
    out[1] = vt * 0.5f;
  }
}

extern "C" void kernel_launch(void* const* d_in, const int* in_sizes, int n_in,
                              void* d_out, int out_size, void* d_ws, size_t ws_size,
                              hipStream_t stream) {
  const float* patch = (const float*)d_in[0];
  const float* noun  = (const float*)d_in[1];
  const float* gimg  = (const float*)d_in[2];
  const float* gtxt  = (const float*)d_in[3];
  const float* lsc   = (const float*)d_in[4];
  const int*   idx   = (const int*)d_in[5];
  float* out = (float*)d_out;
  float* ws  = (float*)d_ws;

  // out[2] is accumulated with atomics; harness poisons d_out with 0xAA.
  hipMemsetAsync(d_out, 0, 3 * sizeof(float), stream);
  k_main<<<dim3(NB * QPB + NB), dim3(64), 0, stream>>>(patch, noun, gimg, gtxt, ws);
  k_final<<<dim3(NB + 1), dim3(64), 0, stream>>>(ws, lsc, idx, out);
}

// Round 2
// 150.192 us; speedup vs baseline: 1.4176x; 1.4176x over previous
//
#include <hip/hip_runtime.h>
#include <hip/hip_bf16.h>
#include <math.h>

#define NB 64      // batch
#define NN 576     // patches
#define ND 512     // dim
#define NM 16      // nouns
#define QPB 9      // fine blocks per batch element (64 patches each)
#define NPB 64     // patches per fine block
#define NW 4       // waves per fine block (split D)
#define DPW 128    // d-range per wave
#define CH 32      // floats per chunk (per patch)
#define NCHW 4     // chunks per wave (4*32 = 128)
#define LSTR 36    // padded LDS row stride (floats); 144 B -> 16B-aligned rows
#define WVF (NPB * LSTR)   // 2304 floats per wave-private staging buffer
#define KPOS 5
#define TINV 14.2857142857142857f   // 1/0.07

#define WS_REC_OFF 4096             // after 64*64 scores
#define RECSZ 144                   // floats per fine-block record

#define FINF __builtin_inff()

// insert v into desc-sorted 5-list (constant indices only -> stays in VGPRs)
__device__ __forceinline__ void ins5(float (&a)[5], float v) {
  if (v > a[4]) {
    a[4] = v;
    if (a[4] > a[3]) { float x = a[4]; a[4] = a[3]; a[3] = x; }
    if (a[3] > a[2]) { float x = a[3]; a[3] = a[2]; a[2] = x; }
    if (a[2] > a[1]) { float x = a[2]; a[2] = a[1]; a[1] = x; }
    if (a[1] > a[0]) { float x = a[1]; a[1] = a[0]; a[0] = x; }
  }
}

// top-5 of union of two desc-sorted 5-lists, branch-free fixed-index rank merge
__device__ __forceinline__ void merge5(float (&a)[5], const float (&b)[5]) {
  float r[5];
#pragma unroll
  for (int k = 0; k < 5; ++k) {
    float best = -FINF;
#pragma unroll
    for (int i = 0; i <= k + 1; ++i) {
      const int j = k + 1 - i;
      const float av = (i == 0) ? FINF : a[i - 1];
      const float bv = (j == 0) ? FINF : b[j - 1];
      best = fmaxf(best, fminf(av, bv));
    }
    r[k] = best;
  }
#pragma unroll
  for (int k = 0; k < 5; ++k) a[k] = r[k];
}

__device__ __forceinline__ void merge5_shfl(float (&a)[5], int msk) {
  float o[5];
#pragma unroll
  for (int k = 0; k < 5; ++k) o[k] = __shfl_xor(a[k], msk, 64);
  merge5(a, o);
}

__global__ __launch_bounds__(256) void k_main(
    const float* __restrict__ patch, const float* __restrict__ noun,
    const float* __restrict__ gimg, const float* __restrict__ gtxt,
    float* __restrict__ ws) {
  const int blk = blockIdx.x;
  const int t = threadIdx.x;

  __shared__ float lds[NW * WVF + NM * 65];   // 9216 + 1040 floats = 41 KB

  if (blk >= NB * QPB) {
    // ---- score block: scores[i][j] = <img_i, txt_j>, 4-way D-split ----
    const int i = blk - NB * QPB;
    const int j = t & 63;
    const int qd = t >> 6;
    const float4* ip = (const float4*)(gimg + (size_t)i * ND + qd * DPW);
    const float4* tp = (const float4*)(gtxt + (size_t)j * ND + qd * DPW);
    float acc = 0.f;
#pragma unroll 8
    for (int q = 0; q < DPW / 4; ++q) {
      const float4 a = ip[q];
      const float4 b = tp[q];
      acc += a.x * b.x + a.y * b.y + a.z * b.z + a.w * b.w;
    }
    lds[qd * 64 + j] = acc;
    __syncthreads();
    if (t < 64) ws[i * 64 + t] = lds[t] + lds[64 + t] + lds[128 + t] + lds[192 + t];
    return;
  }

  // ---- fine block: b, 64-patch slice; wave wv owns d-range [wv*128, wv*128+128) ----
  const int b = blk / QPB;
  const int quad = blk - b * QPB;
  const int wv = __builtin_amdgcn_readfirstlane(t >> 6);  // uniform -> scalar addr math
  const int lane = t & 63;

  const float* pbase = patch + ((size_t)b * NN + (size_t)quad * NPB) * ND + wv * DPW;
  const float* nbase = noun + (size_t)b * NM * ND + wv * DPW;
  float* wlds = &lds[wv * WVF];   // wave-private staging buffer: no barriers needed

  float acc[NM];
#pragma unroll
  for (int m = 0; m < NM; ++m) acc[m] = 0.f;

  const int sp = lane >> 3;   // staging patch-row (within group of 8)
  const int sf = lane & 7;    // staging float4 index

  float4 stg[8];
#pragma unroll
  for (int r = 0; r < 8; ++r)
    stg[r] = *(const float4*)(pbase + (size_t)(8 * r + sp) * ND + sf * 4);

  for (int c = 0; c < NCHW; ++c) {
#pragma unroll
    for (int r = 0; r < 8; ++r)
      *(float4*)&wlds[(8 * r + sp) * LSTR + sf * 4] = stg[r];
    if (c + 1 < NCHW) {
      const float* pb2 = pbase + (size_t)(c + 1) * CH;
#pragma unroll
      for (int r = 0; r < 8; ++r)
        stg[r] = *(const float4*)(pb2 + (size_t)(8 * r + sp) * ND + sf * 4);
    }
    // lane owns patch column `lane`; pull its 32-float chunk to registers
    float pf[CH];
    {
      const float4* rowp = (const float4*)&wlds[lane * LSTR];
#pragma unroll
      for (int k = 0; k < 8; ++k) {
        const float4 v = rowp[k];
        pf[4 * k] = v.x; pf[4 * k + 1] = v.y; pf[4 * k + 2] = v.z; pf[4 * k + 3] = v.w;
      }
    }
    const float* nc = nbase + c * CH;   // wave-uniform address -> s_load expected
#pragma unroll 4
    for (int m = 0; m < NM; ++m) {
      const float* np_ = nc + m * ND;
      float s0 = 0.f, s1 = 0.f;
#pragma unroll
      for (int d = 0; d < CH; d += 2) {
        s0 += pf[d] * np_[d];
        s1 += pf[d + 1] * np_[d + 1];
      }
      acc[m] += s0 + s1;
    }
  }

  // ---- cross-wave reduction of partial sims ----
  __syncthreads();   // all waves done with their staging buffers
#pragma unroll
  for (int m = 0; m < NM; ++m) lds[wv * 1024 + m * 64 + lane] = acc[m];
  __syncthreads();
  {
    // 256 threads sum the 4 wave-partials: sim[m][p], scaled by 1/T
    const int m = t >> 4;
    const int p0 = (t & 15) * 4;
    float* simL = &lds[NW * WVF];
#pragma unroll
    for (int i2 = 0; i2 < 4; ++i2) {
      const int p = p0 + i2;
      const float s = (lds[m * 64 + p] + lds[1024 + m * 64 + p] +
                       lds[2048 + m * 64 + p] + lds[3072 + m * 64 + p]) * TINV;
      simL[m * 65 + p] = s;
    }
  }
  __syncthreads();

  float* simL = &lds[NW * WVF];
  float* rec = ws + WS_REC_OFF + (size_t)blk * RECSZ;

  if (wv == 1) {
    // ---- phase 3: mask partials (softplus sum + top5 of pooled/T) ----
    float x = 0.f;
#pragma unroll
    for (int m = 0; m < NM; ++m) x += simL[m * 65 + lane];
    x *= (1.f / 16.f);
    float sxp = (x > 0.f) ? (x + log1pf(expf(-x))) : log1pf(expf(x));
    float t5[5] = {x, -FINF, -FINF, -FINF, -FINF};
#pragma unroll
    for (int msk = 1; msk < 64; msk <<= 1) {
      sxp += __shfl_xor(sxp, msk, 64);
      merge5_shfl(t5, msk);
    }
    if (lane == 0) {
      rec[128] = sxp;
#pragma unroll
      for (int k = 0; k < 5; ++k) rec[129 + k] = t5[k];
    }
  } else if (wv == 0) {
    // ---- phase 2: per-noun row stats over 64 cols (16 rows x 4 segments) ----
    const int rr_ = lane & 15;
    const int h = lane >> 4;
    const float* row = &simL[rr_ * 65 + h * 16];
    float mx = -FINF;
#pragma unroll
    for (int k = 0; k < 16; ++k) mx = fmaxf(mx, row[k]);
    mx = fmaxf(mx, __shfl_xor(mx, 16, 64));
    mx = fmaxf(mx, __shfl_xor(mx, 32, 64));
    float se = 0.f;
    float r5[5] = {-FINF, -FINF, -FINF, -FINF, -FINF};
#pragma unroll
    for (int k = 0; k < 16; ++k) {
      const float v = row[k];
      se += expf(v - mx);
      ins5(r5, v);
    }
    se += __shfl_xor(se, 16, 64);
    se += __shfl_xor(se, 32, 64);
    merge5_shfl(r5, 16);
    merge5_shfl(r5, 32);
    if (h == 0) {
      float* rr = rec + rr_ * 8;
      rr[0] = mx;
      rr[1] = se;
#pragma unroll
      for (int k = 0; k < 5; ++k) rr[2 + k] = r5[k];
    }
  }
}

__global__ __launch_bounds__(64) void k_final(
    const float* __restrict__ ws, const float* __restrict__ lscale,
    const int* __restrict__ idx, float* __restrict__ out) {
  const int blk = blockIdx.x;
  const int t = threadIdx.x;

  if (blk < NB) {
    // ---- merge the 9 quad partials for batch element blk (lane-parallel) ----
    const float* base = ws + WS_REC_OFF + (size_t)blk * QPB * RECSZ;
    const int m = t & 15;
    const int g = t >> 4;               // quad group: g gets quads {g, g+4, (g==0: 8)}
    const int nq = (g == 0) ? 3 : 2;

    float lm[3], ls[3];
    float t5[5] = {-FINF, -FINF, -FINF, -FINF, -FINF};
#pragma unroll
    for (int i = 0; i < 3; ++i) { lm[i] = -FINF; ls[i] = 0.f; }
    float mx = -FINF;
    for (int i = 0; i < nq; ++i) {
      const float* rr = base + (g + 4 * i) * RECSZ + m * 8;
      lm[i] = rr[0]; ls[i] = rr[1];
      mx = fmaxf(mx, rr[0]);
#pragma unroll
      for (int k = 0; k < 5; ++k) ins5(t5, rr[2 + k]);
    }
    mx = fmaxf(mx, __shfl_xor(mx, 16, 64));
    mx = fmaxf(mx, __shfl_xor(mx, 32, 64));
    float S = 0.f;
    for (int i = 0; i < nq; ++i) S += ls[i] * expf(lm[i] - mx);
    S += __shfl_xor(S, 16, 64);
    S += __shfl_xor(S, 32, 64);
    merge5_shfl(t5, 16);
    merge5_shfl(t5, 32);

    float contrib = 0.f;
    if (g == 0) {
      const float lse = mx + logf(S);
      const float st = t5[0] + t5[1] + t5[2] + t5[3] + t5[4];
      contrib = (KPOS * lse - st) * (0.6f / (float)(NB * NM));
    }

    // mask partials on lanes with m==0 (g-split over quads, reduce across g)
    float sp_ = 0.f;
    float u5[5] = {-FINF, -FINF, -FINF, -FINF, -FINF};
    if (m == 0) {
      for (int i = 0; i < nq; ++i) {
        const float* rr = base + (g + 4 * i) * RECSZ + 128;
        sp_ += rr[0];
#pragma unroll
        for (int k = 0; k < 5; ++k) ins5(u5, rr[1 + k]);
      }
    }
    sp_ += __shfl_xor(sp_, 16, 64);
    sp_ += __shfl_xor(sp_, 32, 64);
    merge5_shfl(u5, 16);
    merge5_shfl(u5, 32);
    if (t == 0) {
      const float st = u5[0] + u5[1] + u5[2] + u5[3] + u5[4];
      contrib += (sp_ - st) * (0.4f / (float)(NB * NN));
    }
#pragma unroll
    for (int msk = 1; msk < 64; msk <<= 1) contrib += __shfl_xor(contrib, msk, 64);
    if (t == 0) atomicAdd(out + 2, contrib);
    return;
  }

  // ---- loss_c (CLIP bi-directional CE) + loss_t (triplet), from scores ----
  __shared__ float s[64 * 65];
  __shared__ float dg[64];
  __shared__ int idl[64];
  for (int i = 0; i < 64; ++i) s[i * 65 + t] = ws[i * 64 + t];
  idl[t] = idx[t];
  __syncthreads();
  dg[t] = s[t * 66];
  __syncthreads();
  const float sc = lscale[0];

  float mR = -FINF, mC = -FINF;
  for (int j = 0; j < 64; ++j) {
    mR = fmaxf(mR, sc * s[t * 65 + j]);
    mC = fmaxf(mC, sc * s[j * 65 + t]);
  }
  float seR = 0.f, seC = 0.f;
  for (int j = 0; j < 64; ++j) {
    seR += expf(sc * s[t * 65 + j] - mR);
    seC += expf(sc * s[j * 65 + t] - mC);
  }
  const float lseR = mR + logf(seR);
  const float lseC = mC + logf(seC);

  const int myid = idl[t];
  const float di = dg[t];
  float ps = 0.f, trow = 0.f, tcol = 0.f, cs = 0.f, ci = 0.f;
  for (int j = 0; j < 64; ++j) {
    const float sv = s[t * 65 + j];
    const float svT = s[j * 65 + t];
    if (idl[j] == myid) {
      ps += 1.f;
      trow += sc * sv - lseR;
      tcol += sc * svT - lseC;
    }
    if (j != t) {
      cs += fmaxf(0.f, 0.1f + sv - di);
      ci += fmaxf(0.f, 0.1f + sv - dg[j]);
    }
  }
  float vc = -(trow + tcol) / ps;
  float vt = cs + ci;
#pragma unroll
  for (int msk = 1; msk < 64; msk <<= 1) {
    vc += __shfl_xor(vc, msk, 64);
    vt += __shfl_xor(vt, msk, 64);
  }
  if (t == 0) {
    out[0] = vc * (0.5f / 64.f);
    out[1] = vt * 0.5f;
  }
}

extern "C" void kernel_launch(void* const* d_in, const int* in_sizes, int n_in,
                              void* d_out, int out_size, void* d_ws, size_t ws_size,
                              hipStream_t stream) {
  const float* patch = (const float*)d_in[0];
  const float* noun  = (const float*)d_in[1];
  const float* gimg  = (const float*)d_in[2];
  const float* gtxt  = (const float*)d_in[3];
  const float* lsc   = (const float*)d_in[4];
  const int*   idx   = (const int*)d_in[5];
  float* out = (float*)d_out;
  float* ws  = (float*)d_ws;

  hipMemsetAsync(d_out, 0, 3 * sizeof(float), stream);
  k_main<<<dim3(NB * QPB + NB), dim3(256), 0, stream>>>(patch, noun, gimg, gtxt, ws);
  k_final<<<dim3(NB + 1), dim3(64), 0, stream>>>(ws, lsc, idx, out);
}